// Round 5
// baseline (822.157 us; speedup 1.0000x reference)
//
#include <hip/hip_runtime.h>
#include <math.h>

// BRC loss: per-sample 24x24 Gram of [24][4096] fp32 rows + masked contrastive
// epilogue. R5: no-LDS streaming design. R4's LDS path cost ~35us of ds_read
// serialization (9x re-read redundancy) plus barrier coupling. Now: 4 row-
// groups of 6; 6 waves own the C(4,2) group-pairs; each wave streams its 12
// rows global->registers (L1/L2 absorb the 3x re-read), computes 50 pairs
// (36 cross + 14 assigned within), zero main-loop barriers. Register double-
// buffer (named bufs, unroll-2) overlaps loads with 200 fmas.

#define MROWS 24
#define DIM   4096
#define NIT   16             // 4096 floats / (64 lanes * 4) per iteration

typedef float f32x4 __attribute__((ext_vector_type(4)));

// triangle enumeration over 6 elements incl. diagonal: 21 pairs (i<=j)
__device__ __host__ constexpr int tri_i(int p) {
    int i = 0;
    while (p >= 6 - i) { p -= 6 - i; ++i; }
    return i;
}
__device__ __host__ constexpr int tri_j(int p) {
    int i = 0;
    while (p >= 6 - i) { p -= 6 - i; ++i; }
    return i + p;
}

// wave w -> (GA, GB, RA, RB): group pair + rank of w among the 3 waves
// containing each group (within-group pairs p%3==rank go to this wave)
//   w0:(0,1,0,0) w1:(0,2,1,0) w2:(0,3,2,0) w3:(1,2,1,1) w4:(1,3,2,1) w5:(2,3,2,2)

template<int GA, int GB, int RA, int RB>
__device__ __forceinline__ void wave_work(const float* __restrict__ base,
                                          int lane, float* Gf) {
    const float* pa = base + (size_t)GA * 6 * DIM + lane * 4;
    const float* pb = base + (size_t)GB * 6 * DIM + lane * 4;

    float acc[50];
    #pragma unroll
    for (int p = 0; p < 50; ++p) acc[p] = 0.0f;

    f32x4 A0[6], B0[6], A1[6], B1[6];

    auto load12 = [&](f32x4 (&A)[6], f32x4 (&B)[6], int k) {
        const int off = k * 256;             // floats per iteration step
        #pragma unroll
        for (int r = 0; r < 6; ++r) {
            A[r] = *(const f32x4*)(pa + (size_t)r * DIM + off);
            B[r] = *(const f32x4*)(pb + (size_t)r * DIM + off);
        }
    };
    auto compute = [&](const f32x4 (&A)[6], const f32x4 (&B)[6]) {
        #pragma unroll
        for (int a = 0; a < 6; ++a)
            #pragma unroll
            for (int b = 0; b < 6; ++b)
                #pragma unroll
                for (int e = 0; e < 4; ++e)
                    acc[a * 6 + b] = fmaf(A[a][e], B[b][e], acc[a * 6 + b]);
        #pragma unroll
        for (int p = 0; p < 7; ++p) {        // within-GA pairs (rank RA)
            const int q = 3 * p + RA;
            const int i = tri_i(q), j = tri_j(q);
            #pragma unroll
            for (int e = 0; e < 4; ++e)
                acc[36 + p] = fmaf(A[i][e], A[j][e], acc[36 + p]);
        }
        #pragma unroll
        for (int p = 0; p < 7; ++p) {        // within-GB pairs (rank RB)
            const int q = 3 * p + RB;
            const int i = tri_i(q), j = tri_j(q);
            #pragma unroll
            for (int e = 0; e < 4; ++e)
                acc[43 + p] = fmaf(B[i][e], B[j][e], acc[43 + p]);
        }
    };

    load12(A0, B0, 0);
    #pragma unroll 1
    for (int k = 0; k < NIT; k += 2) {
        if (k + 1 < NIT) load12(A1, B1, k + 1);
        compute(A0, B0);
        if (k + 2 < NIT) load12(A0, B0, k + 2);
        compute(A1, B1);
    }

    // reduce 50 accs across 64 lanes, write to Gf (each pair owned uniquely)
    #pragma unroll
    for (int p = 0; p < 50; ++p) {
        float v = acc[p];
        #pragma unroll
        for (int off = 32; off; off >>= 1)
            v += __shfl_xor(v, off, 64);
        if (lane == 0) {
            int i, j;
            if (p < 36)      { i = GA * 6 + p / 6;  j = GB * 6 + p % 6; }
            else if (p < 43) { int q = 3 * (p - 36) + RA; i = GA * 6 + tri_i(q); j = GA * 6 + tri_j(q); }
            else             { int q = 3 * (p - 43) + RB; i = GB * 6 + tri_i(q); j = GB * 6 + tri_j(q); }
            Gf[i * MROWS + j] = v;
            Gf[j * MROWS + i] = v;
        }
    }
}

__global__ __attribute__((amdgpu_flat_work_group_size(384, 384),
                          amdgpu_waves_per_eu(3, 3)))
void brc_loss_kernel(const float* __restrict__ F, float* __restrict__ out, float scale) {
    __shared__ float Gf[MROWS * MROWS];
    __shared__ float inv_n[MROWS];
    __shared__ float rowv[MROWS];

    const int tid  = threadIdx.x;
    const int lane = tid & 63;
    const int wave = tid >> 6;
    const float* base = F + (size_t)blockIdx.x * (MROWS * DIM);

    switch (wave) {
        case 0:  wave_work<0, 1, 0, 0>(base, lane, Gf); break;
        case 1:  wave_work<0, 2, 1, 0>(base, lane, Gf); break;
        case 2:  wave_work<0, 3, 2, 0>(base, lane, Gf); break;
        case 3:  wave_work<1, 2, 1, 1>(base, lane, Gf); break;
        case 4:  wave_work<1, 3, 2, 1>(base, lane, Gf); break;
        default: wave_work<2, 3, 2, 2>(base, lane, Gf); break;
    }
    __syncthreads();                        // Gf complete

    if (tid < MROWS)
        inv_n[tid] = 1.0f / fmaxf(sqrtf(Gf[tid * MROWS + tid]), 1e-12f);
    __syncthreads();

    if (tid < MROWS) {
        const int i = tid;
        const int ci = i % 12;
        const float inv_i = inv_n[i];
        float denom = 0.0f, possum = 0.0f;
        int cnt = 0;
        for (int j = 0; j < MROWS; ++j) {
            if (j == i) continue;
            float l = Gf[i * MROWS + j] * inv_i * inv_n[j] * (1.0f / 0.1f);
            denom += expf(l);                       // is_stable=False: no max-sub
            int cj = j % 12;
            int dc = ci - cj; if (dc < 0) dc = -dc;
            if (dc <= 1) { possum += l; ++cnt; }    // tiled tridiagonal positives
        }
        float mean = (possum - (float)cnt * logf(denom)) / ((float)cnt + 1e-6f);
        rowv[i] = -0.1f * mean;                     // -(T/BASE_T) * mean_log_prob_pos
    }
    __syncthreads();

    if (tid == 0) {
        float s = 0.0f;
        #pragma unroll
        for (int i = 0; i < MROWS; ++i) s += rowv[i];
        atomicAdd(out, s * scale);                  // scale = 1/(24*B)
    }
}

extern "C" void kernel_launch(void* const* d_in, const int* in_sizes, int n_in,
                              void* d_out, int out_size, void* d_ws, size_t ws_size,
                              hipStream_t stream) {
    (void)n_in; (void)d_ws; (void)ws_size; (void)out_size;
    // inputs: [0] outputs (unused), [1] targets (unused), [2] features
    const float* F = (const float*)d_in[2];
    float* out = (float*)d_out;
    const int B = in_sizes[2] / (2 * 12 * DIM);   // 512
    const float scale = 1.0f / (24.0f * (float)B);

    hipMemsetAsync(d_out, 0, sizeof(float), stream);   // d_out re-poisoned each call
    brc_loss_kernel<<<dim3(B), dim3(384), 0, stream>>>(F, out, scale);
}

// Round 6
// 450.621 us; speedup vs baseline: 1.8245x; 1.8245x over previous
//
#include <hip/hip_runtime.h>
#include <math.h>

// BRC loss: per-sample 24x24 Gram of [24][4096] fp32 rows + masked contrastive
// epilogue. R6 = R4's staged global_load_lds ring + counted vmcnt (proven
// spill-free, FETCH=98MB) x R5's group-pair decomposition (proven correct,
// cuts LDS reads 27->12 per wave-chunk and accs 75->50). All register arrays
// are plain locals with fully-static unrolled indexing -- R5's lambda-captured
// double-buffer arrays went to scratch (WRITE_SIZE 1.26 GB, VGPR=84).

#define MROWS 24
#define DIM   4096
#define CH    256            // columns per LDS chunk (1 KB/row)
#define NCH   (DIM / CH)     // 16 chunks
#define DEPTH 3              // chunk ring buffers in flight

typedef float f32x4 __attribute__((ext_vector_type(4)));

__device__ __forceinline__ void gll16(const float* g, float* l) {
    // async global->LDS, 16B/lane; LDS dest = wave-uniform base + lane*16
    __builtin_amdgcn_global_load_lds(
        (const __attribute__((address_space(1))) unsigned int*)g,
        (__attribute__((address_space(3))) unsigned int*)l, 16, 0, 0);
}

#define WAITV(N) do { \
    asm volatile("s_waitcnt vmcnt(" #N ")" ::: "memory"); \
    __builtin_amdgcn_sched_barrier(0); \
} while (0)
#define FENCE() __builtin_amdgcn_sched_barrier(0)

// triangle enumeration over 6 elements incl. diagonal: 21 pairs (i<=j)
__device__ __host__ constexpr int tri_i(int p) {
    int i = 0;
    while (p >= 6 - i) { p -= 6 - i; ++i; }
    return i;
}
__device__ __host__ constexpr int tri_j(int p) {
    int i = 0;
    while (p >= 6 - i) { p -= 6 - i; ++i; }
    return i + p;
}

// wave W -> groups (GA,GB) + within-group ranks (RA,RB); within-group pairs
// q = 3p + rank (7 each). Coverage verified in R5 (absmax 0).
//   w0:(0,1,0,0) w1:(0,2,1,0) w2:(0,3,2,0) w3:(1,2,1,1) w4:(1,3,2,1) w5:(2,3,2,2)

template<int W, int GA, int GB, int RA, int RB>
__device__ __forceinline__ void wave_main(const float* __restrict__ base,
                                          float (*tile)[MROWS * CH],
                                          int lane, float* Gf) {
    float acc[50];
    #pragma unroll
    for (int p = 0; p < 50; ++p) acc[p] = 0.0f;

    // this wave stages rows 4W..4W+3 of each chunk (one gll16 = 1 KB row)
    auto issue = [&](int k) {
        const float* src = base + k * CH + lane * 4;
        float* dst = &tile[k % DEPTH][0];
        #pragma unroll
        for (int q = 0; q < 4; ++q)
            gll16(src + (size_t)(4 * W + q) * DIM, dst + (4 * W + q) * CH);
    };

    issue(0); issue(1); issue(2);                  // 12 loads in flight

    #pragma unroll 1
    for (int k = 0; k < NCH; ++k) {
        if (k < NCH - 2)       WAITV(8);           // chunk k's 4 loads done
        else if (k == NCH - 2) WAITV(4);
        else                   WAITV(0);
        __builtin_amdgcn_s_barrier();              // chunk k staged by all waves
        FENCE();

        const float* t = &tile[k % DEPTH][0] + lane * 4;
        f32x4 A[6], B[6];
        #pragma unroll
        for (int r = 0; r < 6; ++r) {
            A[r] = *(const f32x4*)(t + (GA * 6 + r) * CH);
            B[r] = *(const f32x4*)(t + (GB * 6 + r) * CH);
        }
        #pragma unroll
        for (int a = 0; a < 6; ++a)
            #pragma unroll
            for (int b = 0; b < 6; ++b)
                #pragma unroll
                for (int e = 0; e < 4; ++e)
                    acc[a * 6 + b] = fmaf(A[a][e], B[b][e], acc[a * 6 + b]);
        #pragma unroll
        for (int p = 0; p < 7; ++p) {              // within-GA pairs, rank RA
            const int i = tri_i(3 * p + RA), j = tri_j(3 * p + RA);
            #pragma unroll
            for (int e = 0; e < 4; ++e)
                acc[36 + p] = fmaf(A[i][e], A[j][e], acc[36 + p]);
        }
        #pragma unroll
        for (int p = 0; p < 7; ++p) {              // within-GB pairs, rank RB
            const int i = tri_i(3 * p + RB), j = tri_j(3 * p + RB);
            #pragma unroll
            for (int e = 0; e < 4; ++e)
                acc[43 + p] = fmaf(B[i][e], B[j][e], acc[43 + p]);
        }

        FENCE();
        __builtin_amdgcn_s_barrier();              // all waves done with slot
        if (k + DEPTH < NCH) issue(k + DEPTH);     // overwrite freed slot
    }

    // reduce 50 accs across 64 lanes; each pair owned by exactly one wave
    #pragma unroll
    for (int p = 0; p < 50; ++p) {
        float v = acc[p];
        #pragma unroll
        for (int off = 32; off; off >>= 1)
            v += __shfl_xor(v, off, 64);
        if (lane == 0) {
            int i, j;
            if (p < 36)      { i = GA * 6 + p / 6;  j = GB * 6 + p % 6; }
            else if (p < 43) { int q = 3 * (p - 36) + RA; i = GA * 6 + tri_i(q); j = GA * 6 + tri_j(q); }
            else             { int q = 3 * (p - 43) + RB; i = GB * 6 + tri_i(q); j = GB * 6 + tri_j(q); }
            Gf[i * MROWS + j] = v;
            Gf[j * MROWS + i] = v;
        }
    }
}

__global__ __launch_bounds__(384)
void brc_loss_kernel(const float* __restrict__ F, float* __restrict__ out, float scale) {
    __shared__ float tile[DEPTH][MROWS * CH];   // 72 KiB ring -> 2 blocks/CU
    __shared__ float Gf[MROWS * MROWS];
    __shared__ float inv_n[MROWS];
    __shared__ float rowv[MROWS];

    const int tid  = threadIdx.x;
    const int lane = tid & 63;
    const int wave = tid >> 6;
    const float* base = F + (size_t)blockIdx.x * (MROWS * DIM);

    switch (wave) {
        case 0:  wave_main<0, 0, 1, 0, 0>(base, tile, lane, Gf); break;
        case 1:  wave_main<1, 0, 2, 1, 0>(base, tile, lane, Gf); break;
        case 2:  wave_main<2, 0, 3, 2, 0>(base, tile, lane, Gf); break;
        case 3:  wave_main<3, 1, 2, 1, 1>(base, tile, lane, Gf); break;
        case 4:  wave_main<4, 1, 3, 2, 1>(base, tile, lane, Gf); break;
        default: wave_main<5, 2, 3, 2, 2>(base, tile, lane, Gf); break;
    }
    __syncthreads();                        // Gf complete

    if (tid < MROWS)
        inv_n[tid] = 1.0f / fmaxf(sqrtf(Gf[tid * MROWS + tid]), 1e-12f);
    __syncthreads();

    if (tid < MROWS) {
        const int i = tid;
        const int ci = i % 12;
        const float inv_i = inv_n[i];
        float denom = 0.0f, possum = 0.0f;
        int cnt = 0;
        for (int j = 0; j < MROWS; ++j) {
            if (j == i) continue;
            float l = Gf[i * MROWS + j] * inv_i * inv_n[j] * (1.0f / 0.1f);
            denom += expf(l);                       // is_stable=False: no max-sub
            int cj = j % 12;
            int dc = ci - cj; if (dc < 0) dc = -dc;
            if (dc <= 1) { possum += l; ++cnt; }    // tiled tridiagonal positives
        }
        float mean = (possum - (float)cnt * logf(denom)) / ((float)cnt + 1e-6f);
        rowv[i] = -0.1f * mean;                     // -(T/BASE_T) * mean_log_prob_pos
    }
    __syncthreads();

    if (tid == 0) {
        float s = 0.0f;
        #pragma unroll
        for (int i = 0; i < MROWS; ++i) s += rowv[i];
        atomicAdd(out, s * scale);                  // scale = 1/(24*B)
    }
}

extern "C" void kernel_launch(void* const* d_in, const int* in_sizes, int n_in,
                              void* d_out, int out_size, void* d_ws, size_t ws_size,
                              hipStream_t stream) {
    (void)n_in; (void)d_ws; (void)ws_size; (void)out_size;
    // inputs: [0] outputs (unused), [1] targets (unused), [2] features
    const float* F = (const float*)d_in[2];
    float* out = (float*)d_out;
    const int B = in_sizes[2] / (2 * 12 * DIM);   // 512
    const float scale = 1.0f / (24.0f * (float)B);

    hipMemsetAsync(d_out, 0, sizeof(float), stream);   // d_out re-poisoned each call
    brc_loss_kernel<<<dim3(B), dim3(384), 0, stream>>>(F, out, scale);
}

// Round 7
// 361.557 us; speedup vs baseline: 2.2739x; 1.2463x over previous
//
#include <hip/hip_runtime.h>
#include <math.h>

// BRC loss: per-sample 24x24 Gram of [24][4096] fp32 rows + masked contrastive
// epilogue. R7: finer pair-cover to kill spills by construction. R6 (6 waves,
// acc[50]+48 tile regs ~= 98 live) still spilled 523 MB; allocator won't go
// past ~88-128 VGPRs. Now 6 groups of 4 rows, 15 waves own C(6,2) group-pairs:
// acc[20] + A[4] + B[4] ~= 65 live. 960-thread blocks, 2/CU -> 30 waves/CU.
// Proven depth-3 global_load_lds ring + counted vmcnt (FETCH=103MB clean).

#define MROWS 24
#define DIM   4096
#define CH    256            // columns per LDS chunk (1 KB/row)
#define NCH   (DIM / CH)     // 16 chunks
#define DEPTH 3              // chunk ring buffers in flight

typedef float f32x4 __attribute__((ext_vector_type(4)));

__device__ __forceinline__ void gll16(const float* g, float* l) {
    // async global->LDS, 16B/lane; LDS dest = wave-uniform base + lane*16
    __builtin_amdgcn_global_load_lds(
        (const __attribute__((address_space(1))) unsigned int*)g,
        (__attribute__((address_space(3))) unsigned int*)l, 16, 0, 0);
}

#define WAITV(N) do { \
    asm volatile("s_waitcnt vmcnt(" #N ")" ::: "memory"); \
    __builtin_amdgcn_sched_barrier(0); \
} while (0)
#define FENCE() __builtin_amdgcn_sched_barrier(0)

// triangle enumeration over 4 elements incl. diagonal: 10 pairs (i<=j)
__device__ __host__ constexpr int tri4_i(int p) {
    int i = 0;
    while (p >= 4 - i) { p -= 4 - i; ++i; }
    return i;
}
__device__ __host__ constexpr int tri4_j(int p) {
    int i = 0;
    while (p >= 4 - i) { p -= 4 - i; ++i; }
    return i + p;
}

// Wave W owns group-pair (GA,GB), GA<GB in {0..5}. RA = rank of this wave
// among the 5 waves containing GA (ranks 0..4); within-GA tri pairs
// q = 2*RA, 2*RA+1 go to this wave (5 ranks x 2 = all 10). Same for GB.
// Every group appears in exactly 5 waves -> each of the 300 pairs once.

template<int W, int GA, int GB, int RA, int RB>
__device__ __forceinline__ void wave_main(const float* __restrict__ base,
                                          float (*tile)[MROWS * CH],
                                          int lane, float* Gf) {
    float acc[20];
    #pragma unroll
    for (int p = 0; p < 20; ++p) acc[p] = 0.0f;

    // waves 0..11 stage rows {2W, 2W+1} of each chunk (one gll16 = 1 KB row)
    auto issue = [&](int k) {
        if constexpr (W < 12) {
            const float* src = base + k * CH + lane * 4;
            float* dst = &tile[k % DEPTH][0];
            gll16(src + (size_t)(2 * W) * DIM,     dst + (2 * W) * CH);
            gll16(src + (size_t)(2 * W + 1) * DIM, dst + (2 * W + 1) * CH);
        }
    };

    issue(0); issue(1); issue(2);                  // 6 loads in flight (stagers)

    #pragma unroll 1
    for (int k = 0; k < NCH; ++k) {
        if (k < NCH - 2)       WAITV(4);           // chunk k's 2 loads done
        else if (k == NCH - 2) WAITV(2);
        else                   WAITV(0);
        __builtin_amdgcn_s_barrier();              // chunk k staged by all waves
        FENCE();

        const float* t = &tile[k % DEPTH][0] + lane * 4;
        f32x4 A[4], B[4];
        #pragma unroll
        for (int r = 0; r < 4; ++r) {
            A[r] = *(const f32x4*)(t + (GA * 4 + r) * CH);
            B[r] = *(const f32x4*)(t + (GB * 4 + r) * CH);
        }
        #pragma unroll
        for (int a = 0; a < 4; ++a)
            #pragma unroll
            for (int b = 0; b < 4; ++b)
                #pragma unroll
                for (int e = 0; e < 4; ++e)
                    acc[a * 4 + b] = fmaf(A[a][e], B[b][e], acc[a * 4 + b]);
        #pragma unroll
        for (int p = 0; p < 2; ++p) {              // within-GA pairs, rank RA
            const int i = tri4_i(2 * RA + p), j = tri4_j(2 * RA + p);
            #pragma unroll
            for (int e = 0; e < 4; ++e)
                acc[16 + p] = fmaf(A[i][e], A[j][e], acc[16 + p]);
        }
        #pragma unroll
        for (int p = 0; p < 2; ++p) {              // within-GB pairs, rank RB
            const int i = tri4_i(2 * RB + p), j = tri4_j(2 * RB + p);
            #pragma unroll
            for (int e = 0; e < 4; ++e)
                acc[18 + p] = fmaf(B[i][e], B[j][e], acc[18 + p]);
        }

        FENCE();
        __builtin_amdgcn_s_barrier();              // all waves done with slot
        if (k + DEPTH < NCH) issue(k + DEPTH);     // overwrite freed slot
    }

    // reduce 20 accs across 64 lanes; each pair owned by exactly one wave
    #pragma unroll
    for (int p = 0; p < 20; ++p) {
        float v = acc[p];
        #pragma unroll
        for (int off = 32; off; off >>= 1)
            v += __shfl_xor(v, off, 64);
        if (lane == 0) {
            int i, j;
            if (p < 16)      { i = GA * 4 + p / 4; j = GB * 4 + p % 4; }
            else if (p < 18) { int q = 2 * RA + (p - 16); i = GA * 4 + tri4_i(q); j = GA * 4 + tri4_j(q); }
            else             { int q = 2 * RB + (p - 18); i = GB * 4 + tri4_i(q); j = GB * 4 + tri4_j(q); }
            Gf[i * MROWS + j] = v;
            Gf[j * MROWS + i] = v;
        }
    }
}

__global__ __launch_bounds__(960)
void brc_loss_kernel(const float* __restrict__ F, float* __restrict__ out, float scale) {
    __shared__ float tile[DEPTH][MROWS * CH];   // 72 KiB ring -> 2 blocks/CU
    __shared__ float Gf[MROWS * MROWS];
    __shared__ float inv_n[MROWS];
    __shared__ float rowv[MROWS];

    const int tid  = threadIdx.x;
    const int lane = tid & 63;
    const int wave = tid >> 6;
    const float* base = F + (size_t)blockIdx.x * (MROWS * DIM);

    switch (wave) {
        case 0:  wave_main< 0, 0, 1, 0, 0>(base, tile, lane, Gf); break;
        case 1:  wave_main< 1, 0, 2, 1, 0>(base, tile, lane, Gf); break;
        case 2:  wave_main< 2, 0, 3, 2, 0>(base, tile, lane, Gf); break;
        case 3:  wave_main< 3, 0, 4, 3, 0>(base, tile, lane, Gf); break;
        case 4:  wave_main< 4, 0, 5, 4, 0>(base, tile, lane, Gf); break;
        case 5:  wave_main< 5, 1, 2, 1, 1>(base, tile, lane, Gf); break;
        case 6:  wave_main< 6, 1, 3, 2, 1>(base, tile, lane, Gf); break;
        case 7:  wave_main< 7, 1, 4, 3, 1>(base, tile, lane, Gf); break;
        case 8:  wave_main< 8, 1, 5, 4, 1>(base, tile, lane, Gf); break;
        case 9:  wave_main< 9, 2, 3, 2, 2>(base, tile, lane, Gf); break;
        case 10: wave_main<10, 2, 4, 3, 2>(base, tile, lane, Gf); break;
        case 11: wave_main<11, 2, 5, 4, 2>(base, tile, lane, Gf); break;
        case 12: wave_main<12, 3, 4, 3, 3>(base, tile, lane, Gf); break;
        case 13: wave_main<13, 3, 5, 4, 3>(base, tile, lane, Gf); break;
        default: wave_main<14, 4, 5, 4, 4>(base, tile, lane, Gf); break;
    }
    __syncthreads();                        // Gf complete

    if (tid < MROWS)
        inv_n[tid] = 1.0f / fmaxf(sqrtf(Gf[tid * MROWS + tid]), 1e-12f);
    __syncthreads();

    if (tid < MROWS) {
        const int i = tid;
        const int ci = i % 12;
        const float inv_i = inv_n[i];
        float denom = 0.0f, possum = 0.0f;
        int cnt = 0;
        for (int j = 0; j < MROWS; ++j) {
            if (j == i) continue;
            float l = Gf[i * MROWS + j] * inv_i * inv_n[j] * (1.0f / 0.1f);
            denom += expf(l);                       // is_stable=False: no max-sub
            int cj = j % 12;
            int dc = ci - cj; if (dc < 0) dc = -dc;
            if (dc <= 1) { possum += l; ++cnt; }    // tiled tridiagonal positives
        }
        float mean = (possum - (float)cnt * logf(denom)) / ((float)cnt + 1e-6f);
        rowv[i] = -0.1f * mean;                     // -(T/BASE_T) * mean_log_prob_pos
    }
    __syncthreads();

    if (tid == 0) {
        float s = 0.0f;
        #pragma unroll
        for (int i = 0; i < MROWS; ++i) s += rowv[i];
        atomicAdd(out, s * scale);                  // scale = 1/(24*B)
    }
}

extern "C" void kernel_launch(void* const* d_in, const int* in_sizes, int n_in,
                              void* d_out, int out_size, void* d_ws, size_t ws_size,
                              hipStream_t stream) {
    (void)n_in; (void)d_ws; (void)ws_size; (void)out_size;
    // inputs: [0] outputs (unused), [1] targets (unused), [2] features
    const float* F = (const float*)d_in[2];
    float* out = (float*)d_out;
    const int B = in_sizes[2] / (2 * 12 * DIM);   // 512
    const float scale = 1.0f / (24.0f * (float)B);

    hipMemsetAsync(d_out, 0, sizeof(float), stream);   // d_out re-poisoned each call
    brc_loss_kernel<<<dim3(B), dim3(960), 0, stream>>>(F, out, scale);
}